// Round 6
// baseline (5193.599 us; speedup 1.0000x reference)
//
#include <hip/hip_runtime.h>
#include <stdint.h>

#define B_DIM 256
#define T_DIM 400
#define I_DIMM 256
#define H_DIM 512
#define KH 512      // hidden K
#define KX 256      // input K
#define KU 768      // unified K
#define MT 32       // batch rows per workgroup
#define ACOLS 32    // phase-A (zr) output cols per wg
#define BCOLS 16    // phase-B (n) output cols per wg
#define LDK 776     // padded LDS row pitch (bf16 elems)

#define LDS_USHORTS (2*ACOLS*LDK + 2*BCOLS*LDK)
#define LDS_BYTES   (LDS_USHORTS*2 + (512 + 1280)*4)   // +red +tpose

// ws layout (bytes)
#define OFF_FLAGA 0
#define OFF_FLAGB 1024
#define OFF_HFRAG 8192
#define FRAG_BYTES (16*16*64*32)          // 512KB
#define OFF_RHFRAG (OFF_HFRAG + FRAG_BYTES)
#define OFF_ZBUF   (OFF_RHFRAG + FRAG_BYTES)
#define OFF_XFRAG  (OFF_ZBUF + B_DIM*H_DIM*4)
#define XFRAG_BYTES ((size_t)T_DIM*16*8*2048)          // 100 MB
#define WS_NEED    ((size_t)OFF_XFRAG + XFRAG_BYTES)

typedef unsigned long long u64;
typedef __attribute__((ext_vector_type(8))) short short8v;
typedef __attribute__((ext_vector_type(4))) float f32x4;
typedef __attribute__((ext_vector_type(4))) unsigned uint4v;
typedef __attribute__((ext_vector_type(2))) u64 u64x2;

__device__ __forceinline__ unsigned short f2bf(float f){
  unsigned u = __builtin_bit_cast(unsigned, f);
  return (unsigned short)((u + 0x7fffu + ((u >> 16) & 1u)) >> 16);   // RNE
}
__device__ __forceinline__ float bf2f(unsigned short u){
  return __builtin_bit_cast(float, ((unsigned)u) << 16);
}
__device__ __forceinline__ f32x4 mfma16(short8v a, short8v b, f32x4 c){
  return __builtin_amdgcn_mfma_f32_16x16x32_bf16(a, b, c, 0, 0, 0);
}

// ---- device-coherent (LLC) access, COMPILER-VISIBLE (spill-safe, auto waitcnt) ----
__device__ __forceinline__ u64 ld64_cg(const void* p){
  return __hip_atomic_load((const u64*)p, __ATOMIC_RELAXED, __HIP_MEMORY_SCOPE_AGENT);
}
__device__ __forceinline__ unsigned ld16_cg(const void* p){
  return (unsigned)__hip_atomic_load((const unsigned short*)p, __ATOMIC_RELAXED,
                                     __HIP_MEMORY_SCOPE_AGENT);
}
// coherent 16B store (inputs read at issue -> safe as asm)
__device__ __forceinline__ void cst128(void* p, uint4v v){
  asm volatile("global_store_dwordx4 %0, %1, off sc0 sc1" :: "v"(p), "v"(v) : "memory");
}
#define VMCNT0() asm volatile("s_waitcnt vmcnt(0)" ::: "memory")

// coalesced poll: each lane loads one u64 (2 flags); lanes 0-15 cover all 32
__device__ __forceinline__ void spin32(const unsigned* f, unsigned target){
  const u64* p = (const u64*)(f + ((threadIdx.x & 15) << 1));
  for (;;){
    u64 v = __hip_atomic_load(p, __ATOMIC_RELAXED, __HIP_MEMORY_SCOPE_AGENT);
    bool ok = ((unsigned)v >= target) & ((unsigned)(v >> 32) >= target);
    if (__all((int)ok)) break;
    __builtin_amdgcn_s_sleep(1);
  }
  asm volatile("" ::: "memory");
}

// fragment address of element (row, col): hi at +0, lo at +16
__device__ __forceinline__ size_t frag_off(int row, int col){
  int fragblk = (row >> 5)*2 + ((row >> 4) & 1);
  int kb   = col >> 5;
  int lane = (row & 15) + (((col & 31) >> 3) << 4);
  int e    = col & 7;
  return (size_t)fragblk*32768 + kb*2048 + lane*32 + e*2;
}

__global__ void gru_init(const float* __restrict__ h0, char* __restrict__ ws){
  int gtid = blockIdx.x * blockDim.x + threadIdx.x;
  if (gtid < 2048) ((unsigned*)ws)[gtid] = 0u;
  char* hfrag = ws + OFF_HFRAG;
  for (int idx = gtid; idx < B_DIM*H_DIM; idx += gridDim.x * blockDim.x){
    float h = h0[idx];
    unsigned short hi = f2bf(h);
    unsigned short lo = f2bf(h - bf2f(hi));
    size_t off = frag_off(idx >> 9, idx & 511);
    *(unsigned short*)(hfrag + off)      = hi;
    *(unsigned short*)(hfrag + off + 16) = lo;
  }
}

// transcode x (fp32) into fragment layout: [t][rb 0..15][kb 0..7][lane][hi16|lo16]
__global__ void x_transcode(const float* __restrict__ x, char* __restrict__ xfrag){
  int gtid = blockIdx.x * blockDim.x + threadIdx.x;
  int w = gtid >> 6, lane = gtid & 63;
  if (w >= T_DIM*16*8) return;
  int t = w >> 7, rem = w & 127, rb = rem >> 3, kb = rem & 7;
  int row = rb*16 + (lane & 15);
  int kq  = (lane >> 4) * 8;
  const float* src = x + ((size_t)row*T_DIM + t)*I_DIMM + kb*32 + kq;
  f32x4 v0 = *(const f32x4*)src;
  f32x4 v1 = *(const f32x4*)(src + 4);
  short8v hi, lo;
  #pragma unroll
  for (int e = 0; e < 4; ++e){
    unsigned short h0b = f2bf(v0[e]), h1b = f2bf(v1[e]);
    hi[e] = (short)h0b;  hi[e+4] = (short)h1b;
    lo[e]   = (short)f2bf(v0[e] - bf2f(h0b));
    lo[e+4] = (short)f2bf(v1[e] - bf2f(h1b));
  }
  char* dst = xfrag + ((size_t)(t*16 + rb)*8 + kb)*2048 + lane*32;
  *(short8v*)dst = hi;
  *(short8v*)(dst + 16) = lo;
}

template<int XF>
__global__ void __launch_bounds__(256, 1) gru_scan(
    const float* __restrict__ x, const float* __restrict__ w_ih,
    const float* __restrict__ b_ih, const float* __restrict__ w_hh,
    const float* __restrict__ b_hh, const float* __restrict__ h0,
    float* __restrict__ out, char* __restrict__ ws)
{
  extern __shared__ unsigned short lds[];
  unsigned short* WAh = lds;
  unsigned short* WAl = WAh + ACOLS*LDK;
  unsigned short* WBh = WAl + ACOLS*LDK;
  unsigned short* WBl = WBh + BCOLS*LDK;
  float* red   = (float*)(WBl + BCOLS*LDK);   // [2][16][16]
  float* tpose = red + 512;                   // 4 waves x [16][20]

  char* hfrag  = ws + OFF_HFRAG;
  char* rhfrag = ws + OFF_RHFRAG;
  float* zbuf  = (float*)(ws + OFF_ZBUF);     // column-major [8 it][512 col][32 row]
  const char* xfrag = ws + OFF_XFRAG;

  const int bid = blockIdx.x;
  const int it  = bid & 7;     // row-tile group
  const int j   = bid >> 3;    // 0..31 hidden slice
  const int tid = threadIdx.x;
  const int lane = tid & 63;
  const int wv   = tid >> 6;
  unsigned* flagsA = (unsigned*)(ws + OFF_FLAGA) + it*32;
  unsigned* flagsB = (unsigned*)(ws + OFF_FLAGB) + it*32;

  // ---- preload weight slices into LDS as bf16 hi/lo ----
  for (int c = 0; c < ACOLS; ++c){
    int g = ACOLS*j + c;
    for (int k = tid; k < KU; k += 256){
      float w = (k < KH) ? w_hh[(size_t)g*KH + k] : w_ih[(size_t)g*KX + (k - KH)];
      unsigned short hi = f2bf(w);
      WAh[c*LDK + k] = hi;
      WAl[c*LDK + k] = f2bf(w - bf2f(hi));
    }
  }
  for (int c = 0; c < BCOLS; ++c){
    int g = 1024 + BCOLS*j + c;
    for (int k = tid; k < KU; k += 256){
      float w = (k < KH) ? w_hh[(size_t)g*KH + k] : w_ih[(size_t)g*KX + (k - KH)];
      unsigned short hi = f2bf(w);
      WBh[c*LDK + k] = hi;
      WBl[c*LDK + k] = f2bf(w - bf2f(hi));
    }
  }
  __syncthreads();

  // ---- per-thread geometry ----
  const int l16 = lane & 15;
  const int lq  = lane >> 4;
  const int kq  = lq * 8;
  const int rowblk  = wv & 1;
  const int colblkA = wv >> 1;
  const int khalf   = wv >> 1;

  const int fragblk = it*2 + rowblk;
  const char* hA_base  = hfrag  + (size_t)fragblk*32768 + lane*32;
  const char* rhB_base = rhfrag + (size_t)fragblk*32768 + lane*32;
  const int arow = it*MT + rowblk*16 + l16;
  const size_t xrow_off = (size_t)arow * (T_DIM*I_DIMM);
  const int ldsA = (colblkA*16 + l16) * LDK;
  const int ldsB = l16 * LDK;

  const int zr = ACOLS*j + colblkA*16 + l16;
  const float biasA = b_ih[zr] + b_hh[zr];
  const int nc = BCOLS*j + l16;
  const float biasB = b_ih[1024 + nc] + b_hh[1024 + nc];
  const int mrow0 = it*MT + rowblk*16 + lq*4;

  const int hcs = zr & 511;                      // r-producer h col (valid for all j)
  size_t off_hv[4];
  #pragma unroll
  for (int r = 0; r < 4; ++r) off_hv[r] = frag_off(mrow0 + r, hcs);

  // exchange addresses
  float* zst = zbuf + ((size_t)it*512 + hcs)*32 + rowblk*16 + lq*4;  // j<16: hcs==zr
  const float* zld = zbuf + ((size_t)it*512 + nc)*32 + rowblk*16 + lq*4;
  char* rhkb = rhfrag + (size_t)fragblk*32768 + (size_t)((j - 16) & 15)*2048;
  char* hkb  = hfrag  + (size_t)fragblk*32768 + (size_t)(j >> 1)*2048;

  u64 hb0[4][4], hb1[4][4];

  auto LDH = [&](u64 (&buf)[4][4], int c0){
    #pragma unroll
    for (int u = 0; u < 4; ++u){
      const char* p = hA_base + (size_t)(c0*4 + u)*2048;
      buf[u][0] = ld64_cg(p);      buf[u][1] = ld64_cg(p + 8);
      buf[u][2] = ld64_cg(p + 16); buf[u][3] = ld64_cg(p + 24);
    }
  };
  auto PRA = [&](u64 (&buf)[4][4], int c0, f32x4& D){
    #pragma unroll
    for (int u = 0; u < 4; ++u){
      int k0 = (c0*4 + u)*32 + kq;
      u64x2 thi = {buf[u][0], buf[u][1]};
      u64x2 tlo = {buf[u][2], buf[u][3]};
      short8v ah = __builtin_bit_cast(short8v, thi);
      short8v al = __builtin_bit_cast(short8v, tlo);
      short8v bh = *(const short8v*)(WAh + ldsA + k0);
      short8v bl = *(const short8v*)(WAl + ldsA + k0);
      D = mfma16(ah, bh, D); D = mfma16(ah, bl, D); D = mfma16(al, bh, D);
    }
  };
  auto LDR = [&](u64 (&buf)[4][4], int c0){
    #pragma unroll
    for (int u = 0; u < 4; ++u){
      const char* p = rhB_base + (size_t)((khalf*8) + c0*4 + u)*2048;
      buf[u][0] = ld64_cg(p);      buf[u][1] = ld64_cg(p + 8);
      buf[u][2] = ld64_cg(p + 16); buf[u][3] = ld64_cg(p + 24);
    }
  };
  auto PRB = [&](u64 (&buf)[4][4], int c0, f32x4& D){
    #pragma unroll
    for (int u = 0; u < 4; ++u){
      int k0 = ((khalf*8) + c0*4 + u)*32 + kq;
      u64x2 thi = {buf[u][0], buf[u][1]};
      u64x2 tlo = {buf[u][2], buf[u][3]};
      short8v ah = __builtin_bit_cast(short8v, thi);
      short8v al = __builtin_bit_cast(short8v, tlo);
      short8v bh = *(const short8v*)(WBh + ldsB + k0);
      short8v bl = *(const short8v*)(WBl + ldsB + k0);
      D = mfma16(ah, bh, D); D = mfma16(ah, bl, D); D = mfma16(al, bh, D);
    }
  };
  auto XCONV = [&](const float* xp, short8v& ah, short8v& al){
    f32x4 v0 = *(const f32x4*)xp;
    f32x4 v1 = *(const f32x4*)(xp + 4);
    #pragma unroll
    for (int e = 0; e < 4; ++e){
      unsigned short h0b = f2bf(v0[e]), h1b = f2bf(v1[e]);
      ah[e] = (short)h0b;  ah[e+4] = (short)h1b;
      al[e]   = (short)f2bf(v0[e] - bf2f(h0b));
      al[e+4] = (short)f2bf(v1[e] - bf2f(h1b));
    }
  };
  // 4 C-layout values (rows mrow0+r, one col) -> fragment 16B/lane coherent store
  auto TPOSE = [&](const float (&v)[4], char* fragkb, int colq_base){
    float* tw = tpose + wv*320;                 // wave-local [16][20]
    #pragma unroll
    for (int r = 0; r < 4; ++r) tw[(lq*4 + r)*20 + l16] = v[r];
    int b = (lane >> 4) & 1;
    const float* tr = tpose + wv*320 + (lane & 15)*20 + b*8;
    f32x4 w0 = *(const f32x4*)tr;
    f32x4 w1 = *(const f32x4*)(tr + 4);
    uint4v wd;
    if (lane < 32){
      unsigned h0b=f2bf(w0[0]), h1b=f2bf(w0[1]), h2b=f2bf(w0[2]), h3b=f2bf(w0[3]);
      unsigned h4b=f2bf(w1[0]), h5b=f2bf(w1[1]), h6b=f2bf(w1[2]), h7b=f2bf(w1[3]);
      wd.x = h0b | (h1b<<16); wd.y = h2b | (h3b<<16);
      wd.z = h4b | (h5b<<16); wd.w = h6b | (h7b<<16);
    } else {
      unsigned l0=f2bf(w0[0]-bf2f(f2bf(w0[0]))), l1=f2bf(w0[1]-bf2f(f2bf(w0[1])));
      unsigned l2=f2bf(w0[2]-bf2f(f2bf(w0[2]))), l3=f2bf(w0[3]-bf2f(f2bf(w0[3])));
      unsigned l4=f2bf(w1[0]-bf2f(f2bf(w1[0]))), l5=f2bf(w1[1]-bf2f(f2bf(w1[1])));
      unsigned l6=f2bf(w1[2]-bf2f(f2bf(w1[2]))), l7=f2bf(w1[3]-bf2f(f2bf(w1[3])));
      wd.x = l0 | (l1<<16); wd.y = l2 | (l3<<16);
      wd.z = l4 | (l5<<16); wd.w = l6 | (l7<<16);
    }
    int fl = (lane & 15) + (colq_base + b)*16;
    cst128(fragkb + fl*32 + ((lane < 32) ? 0 : 16), wd);
  };

  float h_reg[4];
  if (khalf == 0){
    #pragma unroll
    for (int r = 0; r < 4; ++r)
      h_reg[r] = h0[(size_t)(mrow0 + r)*H_DIM + nc];
  }

  for (int t = 0; t < T_DIM; ++t){
    const char* xf_base = xfrag + ((size_t)t*16 + fragblk)*8*2048 + lane*32;
    const float* xt = x + (size_t)t * I_DIMM;

    // ================= phase A =================
    f32x4 D = {0.f, 0.f, 0.f, 0.f};
    #pragma unroll
    for (int kb = 0; kb < 8; ++kb){                  // x part, pre-spin
      short8v ah, al;
      if (XF){
        const char* p = xf_base + kb*2048;
        ah = *(const short8v*)p;
        al = *(const short8v*)(p + 16);
      } else {
        XCONV(xt + xrow_off + kb*32 + kq, ah, al);
      }
      int k0 = KH + kb*32 + kq;
      short8v bh = *(const short8v*)(WAh + ldsA + k0);
      short8v bl = *(const short8v*)(WAl + ldsA + k0);
      D = mfma16(ah, bh, D); D = mfma16(ah, bl, D); D = mfma16(al, bh, D);
    }

    spin32(flagsB, (unsigned)t);                     // h(t-1) ready (all 32 producers)

    unsigned hvh[4], hvl[4];                         // r-producer h(t-1) elements
    #pragma unroll
    for (int r = 0; r < 4; ++r){
      hvh[r] = ld16_cg(hfrag + off_hv[r]);
      hvl[r] = ld16_cg(hfrag + off_hv[r] + 16);
    }
    LDH(hb0, 0); LDH(hb1, 1);                        // 2-deep chunk pipeline
    PRA(hb0, 0, D); LDH(hb0, 2);
    PRA(hb1, 1, D); LDH(hb1, 3);
    PRA(hb0, 2, D); PRA(hb1, 3, D);

    if (j < 16){                                     // z producer: col-major 16B store
      f32x4 zq;
      #pragma unroll
      for (int r = 0; r < 4; ++r){
        float a = D[r] + biasA;
        zq[r] = 1.f / (1.f + __expf(-a));
      }
      cst128(zst, __builtin_bit_cast(uint4v, zq));
    } else {                                         // r producer -> rh fragments
      float rhv[4];
      #pragma unroll
      for (int r = 0; r < 4; ++r){
        float a = D[r] + biasA;
        float rv = 1.f / (1.f + __expf(-a));
        rhv[r] = rv * (bf2f((unsigned short)hvh[r]) + bf2f((unsigned short)hvl[r]));
      }
      TPOSE(rhv, rhkb, colblkA*2);
    }
    VMCNT0();
    __syncthreads();
    if (tid == 0)
      __hip_atomic_store(flagsA + j, (unsigned)(t+1), __ATOMIC_RELAXED,
                         __HIP_MEMORY_SCOPE_AGENT);

    // ================= phase B =================
    f32x4 Dn = {0.f, 0.f, 0.f, 0.f};
    #pragma unroll
    for (int u = 0; u < 4; ++u){                     // x part, pre-spin (K split)
      int kb = khalf*4 + u;
      short8v ah, al;
      if (XF){
        const char* p = xf_base + kb*2048;
        ah = *(const short8v*)p;
        al = *(const short8v*)(p + 16);
      } else {
        XCONV(xt + xrow_off + kb*32 + kq, ah, al);
      }
      int k0 = KH + kb*32 + kq;
      short8v bh = *(const short8v*)(WBh + ldsB + k0);
      short8v bl = *(const short8v*)(WBl + ldsB + k0);
      Dn = mfma16(ah, bh, Dn); Dn = mfma16(ah, bl, Dn); Dn = mfma16(al, bh, Dn);
    }

    spin32(flagsA, (unsigned)(t+1));                 // zr/rh ready AND h-reads done

    f32x4 zq = {0.f, 0.f, 0.f, 0.f};
    if (khalf == 0){                                 // z prefetch (2x8B coherent)
      u64 z0 = ld64_cg(zld), z1 = ld64_cg((const char*)zld + 8);
      u64x2 zz = {z0, z1};
      zq = __builtin_bit_cast(f32x4, zz);
    }
    LDR(hb0, 0); LDR(hb1, 1);
    PRB(hb0, 0, Dn);
    PRB(hb1, 1, Dn);

    if (khalf == 1){
      #pragma unroll
      for (int r = 0; r < 4; ++r)
        red[rowblk*256 + (lq*4 + r)*16 + l16] = Dn[r];
    }
    __syncthreads();
    float hn[4];
    if (khalf == 0){
      #pragma unroll
      for (int r = 0; r < 4; ++r){
        float a = Dn[r] + red[rowblk*256 + (lq*4 + r)*16 + l16] + biasB;
        float ea = __expf(2.f * fabsf(a));
        float nv = 1.f - 2.f / (ea + 1.f);
        nv = (a < 0.f) ? -nv : nv;
        float hnv = zq[r]*h_reg[r] + (1.f - zq[r])*nv;
        hnv = fminf(5.f, fmaxf(-5.f, hnv));
        hn[r] = hnv;
        h_reg[r] = hnv;
      }
      TPOSE(hn, hkb, (j & 1)*2);
    }
    VMCNT0();
    __syncthreads();
    if (tid == 0)
      __hip_atomic_store(flagsB + j, (unsigned)(t+1), __ATOMIC_RELAXED,
                         __HIP_MEMORY_SCOPE_AGENT);
    if (khalf == 0){                                 // off-critical-path output
      #pragma unroll
      for (int r = 0; r < 4; ++r){
        int row = mrow0 + r;
        out[(size_t)row*(T_DIM*H_DIM) + (size_t)t*H_DIM + nc] = hn[r];
        if (t == T_DIM - 1)
          out[(size_t)B_DIM*T_DIM*H_DIM + (size_t)row*H_DIM + nc] = hn[r];
      }
    }
  }
}

extern "C" void kernel_launch(void* const* d_in, const int* in_sizes, int n_in,
                              void* d_out, int out_size, void* d_ws, size_t ws_size,
                              hipStream_t stream){
  const float* x    = (const float*)d_in[0];
  const float* h0   = (const float*)d_in[1];
  const float* w_ih = (const float*)d_in[2];
  const float* b_ih = (const float*)d_in[3];
  const float* w_hh = (const float*)d_in[4];
  const float* b_hh = (const float*)d_in[5];
  float* out = (float*)d_out;
  char* ws = (char*)d_ws;

  gru_init<<<128, 256, 0, stream>>>(h0, ws);

  if (ws_size >= WS_NEED){
    x_transcode<<<(T_DIM*16*8*64 + 255)/256, 256, 0, stream>>>(x, ws + OFF_XFRAG);
    hipFuncSetAttribute((const void*)gru_scan<1>,
                        hipFuncAttributeMaxDynamicSharedMemorySize, LDS_BYTES);
    gru_scan<1><<<256, 256, LDS_BYTES, stream>>>(x, w_ih, b_ih, w_hh, b_hh, h0, out, ws);
  } else {
    hipFuncSetAttribute((const void*)gru_scan<0>,
                        hipFuncAttributeMaxDynamicSharedMemorySize, LDS_BYTES);
    gru_scan<0><<<256, 256, LDS_BYTES, stream>>>(x, w_ih, b_ih, w_hh, b_hh, h0, out, ws);
  }
}

// Round 7
// 4894.461 us; speedup vs baseline: 1.0611x; 1.0611x over previous
//
#include <hip/hip_runtime.h>
#include <stdint.h>

#define B_DIM 256
#define T_DIM 400
#define I_DIMM 256
#define H_DIM 512
#define KH 512      // hidden K
#define KX 256      // input K
#define KU 768      // unified K
#define MT 32       // batch rows per workgroup
#define ACOLS 32    // phase-A (zr) output cols per wg
#define BCOLS 16    // phase-B (n) output cols per wg
#define LDK 772     // padded LDS row pitch (bf16 elems)

#define LDS_USHORTS (2*ACOLS*LDK + 2*BCOLS*LDK)
#define LDS_BYTES   (LDS_USHORTS*2 + (1024 + 640)*4)   // +red[2][2][256] +tpose[2][320]

// ws layout (bytes)
#define OFF_FLAGA 0
#define OFF_FLAGB 1024
#define OFF_HFRAG 8192
#define FRAG_BYTES (16*16*64*32)          // 512KB
#define OFF_RHFRAG (OFF_HFRAG + FRAG_BYTES)
#define OFF_ZBUF   (OFF_RHFRAG + FRAG_BYTES)
#define OFF_XFRAG  (OFF_ZBUF + B_DIM*H_DIM*4)
#define XFRAG_BYTES ((size_t)T_DIM*16*8*2048)          // 100 MB
#define WS_NEED    ((size_t)OFF_XFRAG + XFRAG_BYTES)

typedef unsigned long long u64;
typedef __attribute__((ext_vector_type(8))) short short8v;
typedef __attribute__((ext_vector_type(4))) float f32x4;
typedef __attribute__((ext_vector_type(4))) unsigned uint4v;
typedef __attribute__((ext_vector_type(2))) u64 u64x2;

__device__ __forceinline__ unsigned short f2bf(float f){
  unsigned u = __builtin_bit_cast(unsigned, f);
  return (unsigned short)((u + 0x7fffu + ((u >> 16) & 1u)) >> 16);   // RNE
}
__device__ __forceinline__ float bf2f(unsigned short u){
  return __builtin_bit_cast(float, ((unsigned)u) << 16);
}
__device__ __forceinline__ f32x4 mfma16(short8v a, short8v b, f32x4 c){
  return __builtin_amdgcn_mfma_f32_16x16x32_bf16(a, b, c, 0, 0, 0);
}

// ---- device-coherent (LLC) access, COMPILER-VISIBLE (spill-safe, auto waitcnt) ----
__device__ __forceinline__ u64 ld64_cg(const void* p){
  return __hip_atomic_load((const u64*)p, __ATOMIC_RELAXED, __HIP_MEMORY_SCOPE_AGENT);
}
__device__ __forceinline__ unsigned ld16_cg(const void* p){
  return (unsigned)__hip_atomic_load((const unsigned short*)p, __ATOMIC_RELAXED,
                                     __HIP_MEMORY_SCOPE_AGENT);
}
// coherent 16B store (inputs read at issue -> safe as asm)
__device__ __forceinline__ void cst128(void* p, uint4v v){
  asm volatile("global_store_dwordx4 %0, %1, off sc0 sc1" :: "v"(p), "v"(v) : "memory");
}
#define VMCNT0() asm volatile("s_waitcnt vmcnt(0)" ::: "memory")

// coalesced poll: each lane loads one u64 (2 flags); lanes 0-15 cover all 32
__device__ __forceinline__ void spin32(const unsigned* f, unsigned target){
  const u64* p = (const u64*)(f + ((threadIdx.x & 15) << 1));
  for (;;){
    u64 v = __hip_atomic_load(p, __ATOMIC_RELAXED, __HIP_MEMORY_SCOPE_AGENT);
    bool ok = ((unsigned)v >= target) & ((unsigned)(v >> 32) >= target);
    if (__all((int)ok)) break;
    __builtin_amdgcn_s_sleep(1);
  }
  asm volatile("" ::: "memory");
}

// fragment address of element (row, col): hi at +0, lo at +16
__device__ __forceinline__ size_t frag_off(int row, int col){
  int fragblk = (row >> 5)*2 + ((row >> 4) & 1);
  int kb   = col >> 5;
  int lane = (row & 15) + (((col & 31) >> 3) << 4);
  int e    = col & 7;
  return (size_t)fragblk*32768 + kb*2048 + lane*32 + e*2;
}

__global__ void gru_init(const float* __restrict__ h0, char* __restrict__ ws){
  int gtid = blockIdx.x * blockDim.x + threadIdx.x;
  if (gtid < 2048) ((unsigned*)ws)[gtid] = 0u;
  char* hfrag = ws + OFF_HFRAG;
  for (int idx = gtid; idx < B_DIM*H_DIM; idx += gridDim.x * blockDim.x){
    float h = h0[idx];
    unsigned short hi = f2bf(h);
    unsigned short lo = f2bf(h - bf2f(hi));
    size_t off = frag_off(idx >> 9, idx & 511);
    *(unsigned short*)(hfrag + off)      = hi;
    *(unsigned short*)(hfrag + off + 16) = lo;
  }
}

// transcode x (fp32) into fragment layout: [t][rb 0..15][kb 0..7][lane][hi16|lo16]
__global__ void x_transcode(const float* __restrict__ x, char* __restrict__ xfrag){
  int gtid = blockIdx.x * blockDim.x + threadIdx.x;
  int w = gtid >> 6, lane = gtid & 63;
  if (w >= T_DIM*16*8) return;
  int t = w >> 7, rem = w & 127, rb = rem >> 3, kb = rem & 7;
  int row = rb*16 + (lane & 15);
  int kq  = (lane >> 4) * 8;
  const float* src = x + ((size_t)row*T_DIM + t)*I_DIMM + kb*32 + kq;
  f32x4 v0 = *(const f32x4*)src;
  f32x4 v1 = *(const f32x4*)(src + 4);
  short8v hi, lo;
  #pragma unroll
  for (int e = 0; e < 4; ++e){
    unsigned short h0b = f2bf(v0[e]), h1b = f2bf(v1[e]);
    hi[e] = (short)h0b;  hi[e+4] = (short)h1b;
    lo[e]   = (short)f2bf(v0[e] - bf2f(h0b));
    lo[e+4] = (short)f2bf(v1[e] - bf2f(h1b));
  }
  char* dst = xfrag + ((size_t)(t*16 + rb)*8 + kb)*2048 + lane*32;
  *(short8v*)dst = hi;
  *(short8v*)(dst + 16) = lo;
}

template<int XF>
__global__ void __launch_bounds__(256, 1) gru_scan(
    const float* __restrict__ x, const float* __restrict__ w_ih,
    const float* __restrict__ b_ih, const float* __restrict__ w_hh,
    const float* __restrict__ b_hh, const float* __restrict__ h0,
    float* __restrict__ out, char* __restrict__ ws)
{
  extern __shared__ unsigned short lds[];
  unsigned short* WAh = lds;
  unsigned short* WAl = WAh + ACOLS*LDK;
  unsigned short* WBh = WAl + ACOLS*LDK;
  unsigned short* WBl = WBh + BCOLS*LDK;
  float* red   = (float*)(WBl + BCOLS*LDK);   // [2 rowblk][2 cb][256]
  float* tpose = red + 1024;                  // 2 waves x [16][20]

  char* hfrag  = ws + OFF_HFRAG;
  char* rhfrag = ws + OFF_RHFRAG;
  float* zbuf  = (float*)(ws + OFF_ZBUF);     // column-major [8 it][512 col][32 row]
  const char* xfrag = ws + OFF_XFRAG;

  const int bid = blockIdx.x;
  const int it  = bid & 7;     // row-tile group
  const int j   = bid >> 3;    // 0..31 hidden slice
  const int tid = threadIdx.x;
  const int lane = tid & 63;
  const int wv   = tid >> 6;
  unsigned* flagsA = (unsigned*)(ws + OFF_FLAGA) + it*32;
  unsigned* flagsB = (unsigned*)(ws + OFF_FLAGB) + it*32;

  // ---- preload weight slices into LDS as bf16 hi/lo ----
  for (int c = 0; c < ACOLS; ++c){
    int g = ACOLS*j + c;
    for (int k = tid; k < KU; k += 256){
      float w = (k < KH) ? w_hh[(size_t)g*KH + k] : w_ih[(size_t)g*KX + (k - KH)];
      unsigned short hi = f2bf(w);
      WAh[c*LDK + k] = hi;
      WAl[c*LDK + k] = f2bf(w - bf2f(hi));
    }
  }
  for (int c = 0; c < BCOLS; ++c){
    int g = 1024 + BCOLS*j + c;
    for (int k = tid; k < KU; k += 256){
      float w = (k < KH) ? w_hh[(size_t)g*KH + k] : w_ih[(size_t)g*KX + (k - KH)];
      unsigned short hi = f2bf(w);
      WBh[c*LDK + k] = hi;
      WBl[c*LDK + k] = f2bf(w - bf2f(hi));
    }
  }
  __syncthreads();

  // ---- per-thread geometry: waves = (rowblk, khalf) in BOTH phases ----
  const int l16 = lane & 15;
  const int lq  = lane >> 4;
  const int kq  = lq * 8;
  const int rowblk = wv & 1;
  const int khalf  = wv >> 1;

  const int fragblk = it*2 + rowblk;
  const char* hA_base  = hfrag  + (size_t)fragblk*32768 + lane*32;
  const char* rhB_base = rhfrag + (size_t)fragblk*32768 + lane*32;
  const int arow = it*MT + rowblk*16 + l16;
  const size_t xrow_off = (size_t)arow * (T_DIM*I_DIMM);
  const int ldsA0 = l16 * LDK;                 // cb0 weight rows
  const int ldsA1 = (16 + l16) * LDK;          // cb1 weight rows
  const int ldsB  = l16 * LDK;

  const int zr0 = ACOLS*j + l16;               // phase-A out col, cb0
  const int zr1 = zr0 + 16;                    // cb1
  const float biasA0 = b_ih[zr0] + b_hh[zr0];
  const float biasA1 = b_ih[zr1] + b_hh[zr1];
  const int nc = BCOLS*j + l16;
  const float biasB = b_ih[1024 + nc] + b_hh[1024 + nc];
  const int mrow0 = it*MT + rowblk*16 + lq*4;

  const int hcs0 = zr0 & 511;                  // r-producer h cols (valid addr all j)
  const int hcs1 = zr1 & 511;
  size_t off_hv0[4], off_hv1[4];
  #pragma unroll
  for (int r = 0; r < 4; ++r){
    off_hv0[r] = frag_off(mrow0 + r, hcs0);
    off_hv1[r] = frag_off(mrow0 + r, hcs1);
  }

  // exchange addresses
  float* zst0 = zbuf + ((size_t)it*512 + hcs0)*32 + rowblk*16 + lq*4;  // j<16: hcs==zr
  float* zst1 = zbuf + ((size_t)it*512 + hcs1)*32 + rowblk*16 + lq*4;
  const float* zld = zbuf + ((size_t)it*512 + nc)*32 + rowblk*16 + lq*4;
  char* rhkb = rhfrag + (size_t)fragblk*32768 + (size_t)((j - 16) & 15)*2048;
  char* hkb  = hfrag  + (size_t)fragblk*32768 + (size_t)(j >> 1)*2048;

  u64 hb0[2][4], hb1[2][4];                    // 2-kb chunks

  // ---- chunk loaders/consumers (cc = wave-local chunk 0..3, kb = khalf*8+cc*2+u) ----
  auto LDH2 = [&](u64 (&buf)[2][4], int cc){
    #pragma unroll
    for (int u = 0; u < 2; ++u){
      const char* p = hA_base + (size_t)(khalf*8 + cc*2 + u)*2048;
      buf[u][0] = ld64_cg(p);      buf[u][1] = ld64_cg(p + 8);
      buf[u][2] = ld64_cg(p + 16); buf[u][3] = ld64_cg(p + 24);
    }
  };
  auto PRA2 = [&](u64 (&buf)[2][4], int cc, f32x4& D0, f32x4& D1){
    #pragma unroll
    for (int u = 0; u < 2; ++u){
      int k0 = (khalf*8 + cc*2 + u)*32 + kq;
      u64x2 thi = {buf[u][0], buf[u][1]};
      u64x2 tlo = {buf[u][2], buf[u][3]};
      short8v ah = __builtin_bit_cast(short8v, thi);
      short8v al = __builtin_bit_cast(short8v, tlo);
      short8v bh0 = *(const short8v*)(WAh + ldsA0 + k0);
      short8v bl0 = *(const short8v*)(WAl + ldsA0 + k0);
      D0 = mfma16(ah, bh0, D0); D0 = mfma16(ah, bl0, D0); D0 = mfma16(al, bh0, D0);
      short8v bh1 = *(const short8v*)(WAh + ldsA1 + k0);
      short8v bl1 = *(const short8v*)(WAl + ldsA1 + k0);
      D1 = mfma16(ah, bh1, D1); D1 = mfma16(ah, bl1, D1); D1 = mfma16(al, bh1, D1);
    }
  };
  auto LDR2 = [&](u64 (&buf)[2][4], int cc){
    #pragma unroll
    for (int u = 0; u < 2; ++u){
      const char* p = rhB_base + (size_t)(khalf*8 + cc*2 + u)*2048;
      buf[u][0] = ld64_cg(p);      buf[u][1] = ld64_cg(p + 8);
      buf[u][2] = ld64_cg(p + 16); buf[u][3] = ld64_cg(p + 24);
    }
  };
  auto PRB2 = [&](u64 (&buf)[2][4], int cc, f32x4& D){
    #pragma unroll
    for (int u = 0; u < 2; ++u){
      int k0 = (khalf*8 + cc*2 + u)*32 + kq;
      u64x2 thi = {buf[u][0], buf[u][1]};
      u64x2 tlo = {buf[u][2], buf[u][3]};
      short8v ah = __builtin_bit_cast(short8v, thi);
      short8v al = __builtin_bit_cast(short8v, tlo);
      short8v bh = *(const short8v*)(WBh + ldsB + k0);
      short8v bl = *(const short8v*)(WBl + ldsB + k0);
      D = mfma16(ah, bh, D); D = mfma16(ah, bl, D); D = mfma16(al, bh, D);
    }
  };
  auto XCONV = [&](const float* xp, short8v& ah, short8v& al){
    f32x4 v0 = *(const f32x4*)xp;
    f32x4 v1 = *(const f32x4*)(xp + 4);
    #pragma unroll
    for (int e = 0; e < 4; ++e){
      unsigned short h0b = f2bf(v0[e]), h1b = f2bf(v1[e]);
      ah[e] = (short)h0b;  ah[e+4] = (short)h1b;
      al[e]   = (short)f2bf(v0[e] - bf2f(h0b));
      al[e+4] = (short)f2bf(v1[e] - bf2f(h1b));
    }
  };
  // 4 C-layout values (rows mrow0+r, one col) -> fragment 16B/lane coherent store
  auto TPOSE = [&](const float (&v)[4], char* fragkb, int colq_base){
    float* tw = tpose + wv*320;                 // khalf0 waves: wv 0,1
    #pragma unroll
    for (int r = 0; r < 4; ++r) tw[(lq*4 + r)*20 + l16] = v[r];
    int b = (lane >> 4) & 1;
    const float* tr = tpose + wv*320 + (lane & 15)*20 + b*8;
    f32x4 w0 = *(const f32x4*)tr;
    f32x4 w1 = *(const f32x4*)(tr + 4);
    uint4v wd;
    if (lane < 32){
      unsigned h0b=f2bf(w0[0]), h1b=f2bf(w0[1]), h2b=f2bf(w0[2]), h3b=f2bf(w0[3]);
      unsigned h4b=f2bf(w1[0]), h5b=f2bf(w1[1]), h6b=f2bf(w1[2]), h7b=f2bf(w1[3]);
      wd.x = h0b | (h1b<<16); wd.y = h2b | (h3b<<16);
      wd.z = h4b | (h5b<<16); wd.w = h6b | (h7b<<16);
    } else {
      unsigned l0=f2bf(w0[0]-bf2f(f2bf(w0[0]))), l1=f2bf(w0[1]-bf2f(f2bf(w0[1])));
      unsigned l2=f2bf(w0[2]-bf2f(f2bf(w0[2]))), l3=f2bf(w0[3]-bf2f(f2bf(w0[3])));
      unsigned l4=f2bf(w1[0]-bf2f(f2bf(w1[0]))), l5=f2bf(w1[1]-bf2f(f2bf(w1[1])));
      unsigned l6=f2bf(w1[2]-bf2f(f2bf(w1[2]))), l7=f2bf(w1[3]-bf2f(f2bf(w1[3])));
      wd.x = l0 | (l1<<16); wd.y = l2 | (l3<<16);
      wd.z = l4 | (l5<<16); wd.w = l6 | (l7<<16);
    }
    int fl = (lane & 15) + (colq_base + b)*16;
    cst128(fragkb + fl*32 + ((lane < 32) ? 0 : 16), wd);
  };

  float h_reg[4];
  if (khalf == 0){
    #pragma unroll
    for (int r = 0; r < 4; ++r)
      h_reg[r] = h0[(size_t)(mrow0 + r)*H_DIM + nc];
  }

  const int rotA = j & 3;                       // burst-spreading rotations
  const int rotB = (j >> 2) & 3;

  for (int t = 0; t < T_DIM; ++t){
    const char* xf_base = xfrag + ((size_t)t*16 + fragblk)*8*2048 + lane*32;
    const float* xt = x + (size_t)t * I_DIMM;

    // ================= phase A (K-split: this wave covers kbs khalf*8..+7) ========
    f32x4 D0 = {0.f,0.f,0.f,0.f}, D1 = {0.f,0.f,0.f,0.f};
    #pragma unroll
    for (int u = 0; u < 4; ++u){                // x part: kbs khalf*4..+3, both cbs
      int kb = khalf*4 + u;
      short8v ah, al;
      if (XF){
        const char* p = xf_base + kb*2048;
        ah = *(const short8v*)p;
        al = *(const short8v*)(p + 16);
      } else {
        XCONV(xt + xrow_off + kb*32 + kq, ah, al);
      }
      int k0 = KH + kb*32 + kq;
      short8v bh0 = *(const short8v*)(WAh + ldsA0 + k0);
      short8v bl0 = *(const short8v*)(WAl + ldsA0 + k0);
      D0 = mfma16(ah, bh0, D0); D0 = mfma16(ah, bl0, D0); D0 = mfma16(al, bh0, D0);
      short8v bh1 = *(const short8v*)(WAh + ldsA1 + k0);
      short8v bl1 = *(const short8v*)(WAl + ldsA1 + k0);
      D1 = mfma16(ah, bh1, D1); D1 = mfma16(ah, bl1, D1); D1 = mfma16(al, bh1, D1);
    }

    spin32(flagsB, (unsigned)t);                // h(t-1) ready (all 32 producers)

    unsigned hv0h[4], hv0l[4], hv1h[4], hv1l[4];
    if (khalf == 0){                            // r-producer h(t-1) elements
      #pragma unroll
      for (int r = 0; r < 4; ++r){
        hv0h[r] = ld16_cg(hfrag + off_hv0[r]);
        hv0l[r] = ld16_cg(hfrag + off_hv0[r] + 16);
        hv1h[r] = ld16_cg(hfrag + off_hv1[r]);
        hv1l[r] = ld16_cg(hfrag + off_hv1[r] + 16);
      }
    }
    // h part: 4 chunks x 2kb, rotated start, 2-deep pipeline
    LDH2(hb0, (rotA+0)&3); LDH2(hb1, (rotA+1)&3);
    PRA2(hb0, (rotA+0)&3, D0, D1); LDH2(hb0, (rotA+2)&3);
    PRA2(hb1, (rotA+1)&3, D0, D1); LDH2(hb1, (rotA+3)&3);
    PRA2(hb0, (rotA+2)&3, D0, D1);
    PRA2(hb1, (rotA+3)&3, D0, D1);

    if (khalf == 1){                            // K-reduce: write partials
      #pragma unroll
      for (int r = 0; r < 4; ++r){
        red[(rowblk*2 + 0)*256 + (lq*4 + r)*16 + l16] = D0[r];
        red[(rowblk*2 + 1)*256 + (lq*4 + r)*16 + l16] = D1[r];
      }
    }
    __syncthreads();
    if (khalf == 0){
      #pragma unroll
      for (int r = 0; r < 4; ++r){
        D0[r] += red[(rowblk*2 + 0)*256 + (lq*4 + r)*16 + l16];
        D1[r] += red[(rowblk*2 + 1)*256 + (lq*4 + r)*16 + l16];
      }
      if (j < 16){                              // z producer: two col-major 16B stores
        f32x4 zq0, zq1;
        #pragma unroll
        for (int r = 0; r < 4; ++r){
          zq0[r] = 1.f / (1.f + __expf(-(D0[r] + biasA0)));
          zq1[r] = 1.f / (1.f + __expf(-(D1[r] + biasA1)));
        }
        cst128(zst0, __builtin_bit_cast(uint4v, zq0));
        cst128(zst1, __builtin_bit_cast(uint4v, zq1));
      } else {                                  // r producer -> rh fragments
        float rhv0[4], rhv1[4];
        #pragma unroll
        for (int r = 0; r < 4; ++r){
          float rv0 = 1.f / (1.f + __expf(-(D0[r] + biasA0)));
          float rv1 = 1.f / (1.f + __expf(-(D1[r] + biasA1)));
          rhv0[r] = rv0 * (bf2f((unsigned short)hv0h[r]) + bf2f((unsigned short)hv0l[r]));
          rhv1[r] = rv1 * (bf2f((unsigned short)hv1h[r]) + bf2f((unsigned short)hv1l[r]));
        }
        TPOSE(rhv0, rhkb, 0);
        TPOSE(rhv1, rhkb, 2);
      }
      VMCNT0();
    }
    __syncthreads();
    if (tid == 0)
      __hip_atomic_store(flagsA + j, (unsigned)(t+1), __ATOMIC_RELAXED,
                         __HIP_MEMORY_SCOPE_AGENT);

    // ================= phase B =================
    f32x4 Dn = {0.f, 0.f, 0.f, 0.f};
    #pragma unroll
    for (int u = 0; u < 4; ++u){                // x part, pre-spin (K split)
      int kb = khalf*4 + u;
      short8v ah, al;
      if (XF){
        const char* p = xf_base + kb*2048;
        ah = *(const short8v*)p;
        al = *(const short8v*)(p + 16);
      } else {
        XCONV(xt + xrow_off + kb*32 + kq, ah, al);
      }
      int k0 = KH + kb*32 + kq;
      short8v bh = *(const short8v*)(WBh + ldsB + k0);
      short8v bl = *(const short8v*)(WBl + ldsB + k0);
      Dn = mfma16(ah, bh, Dn); Dn = mfma16(ah, bl, Dn); Dn = mfma16(al, bh, Dn);
    }

    spin32(flagsA, (unsigned)(t+1));            // zr/rh ready AND h-reads done

    f32x4 zq = {0.f, 0.f, 0.f, 0.f};
    if (khalf == 0){                            // z prefetch (2x8B coherent)
      u64 z0 = ld64_cg(zld), z1 = ld64_cg((const char*)zld + 8);
      u64x2 zz = {z0, z1};
      zq = __builtin_bit_cast(f32x4, zz);
    }
    // rh part: 4 chunks x 2kb, rotated, 2-deep pipeline
    LDR2(hb0, (rotB+0)&3); LDR2(hb1, (rotB+1)&3);
    PRB2(hb0, (rotB+0)&3, Dn); LDR2(hb0, (rotB+2)&3);
    PRB2(hb1, (rotB+1)&3, Dn); LDR2(hb1, (rotB+3)&3);
    PRB2(hb0, (rotB+2)&3, Dn);
    PRB2(hb1, (rotB+3)&3, Dn);

    if (khalf == 1){
      #pragma unroll
      for (int r = 0; r < 4; ++r)
        red[rowblk*512 + (lq*4 + r)*16 + l16] = Dn[r];
    }
    __syncthreads();
    float hn[4];
    if (khalf == 0){
      #pragma unroll
      for (int r = 0; r < 4; ++r){
        float a = Dn[r] + red[rowblk*512 + (lq*4 + r)*16 + l16] + biasB;
        float ea = __expf(2.f * fabsf(a));
        float nv = 1.f - 2.f / (ea + 1.f);
        nv = (a < 0.f) ? -nv : nv;
        float hnv = zq[r]*h_reg[r] + (1.f - zq[r])*nv;
        hnv = fminf(5.f, fmaxf(-5.f, hnv));
        hn[r] = hnv;
        h_reg[r] = hnv;
      }
      TPOSE(hn, hkb, (j & 1)*2);
      VMCNT0();
    }
    __syncthreads();
    if (tid == 0)
      __hip_atomic_store(flagsB + j, (unsigned)(t+1), __ATOMIC_RELAXED,
                         __HIP_MEMORY_SCOPE_AGENT);
    if (khalf == 0){                            // off-critical-path output
      #pragma unroll
      for (int r = 0; r < 4; ++r){
        int row = mrow0 + r;
        out[(size_t)row*(T_DIM*H_DIM) + (size_t)t*H_DIM + nc] = hn[r];
        if (t == T_DIM - 1)
          out[(size_t)B_DIM*T_DIM*H_DIM + (size_t)row*H_DIM + nc] = hn[r];
      }
    }
  }
}

extern "C" void kernel_launch(void* const* d_in, const int* in_sizes, int n_in,
                              void* d_out, int out_size, void* d_ws, size_t ws_size,
                              hipStream_t stream){
  const float* x    = (const float*)d_in[0];
  const float* h0   = (const float*)d_in[1];
  const float* w_ih = (const float*)d_in[2];
  const float* b_ih = (const float*)d_in[3];
  const float* w_hh = (const float*)d_in[4];
  const float* b_hh = (const float*)d_in[5];
  float* out = (float*)d_out;
  char* ws = (char*)d_ws;

  gru_init<<<128, 256, 0, stream>>>(h0, ws);

  if (ws_size >= WS_NEED){
    x_transcode<<<(T_DIM*16*8*64 + 255)/256, 256, 0, stream>>>(x, ws + OFF_XFRAG);
    hipFuncSetAttribute((const void*)gru_scan<1>,
                        hipFuncAttributeMaxDynamicSharedMemorySize, LDS_BYTES);
    gru_scan<1><<<256, 256, LDS_BYTES, stream>>>(x, w_ih, b_ih, w_hh, b_hh, h0, out, ws);
  } else {
    hipFuncSetAttribute((const void*)gru_scan<0>,
                        hipFuncAttributeMaxDynamicSharedMemorySize, LDS_BYTES);
    gru_scan<0><<<256, 256, LDS_BYTES, stream>>>(x, w_ih, b_ih, w_hh, b_hh, h0, out, ws);
  }
}